// Round 2
// baseline (468.788 us; speedup 1.0000x reference)
//
#include <hip/hip_runtime.h>

// ---------------------------------------------------------------------------
// GSNet forward, live subgraph only (hk branch is dead in the reference).
// B=4, N=50000, T=12, D=3, HID=32, C=2H=64, R=64.
// Design: wave-per-node, lane=channel. Weights rows in VGPRs, broadcasts via
// v_readlane (VALU), reductions via DPP (VALU). kv/ksum/M are global
// reductions done with raw exp (no max) + post-scale exp(-M), which is exact
// up to fp round-off because num/den is linear in kp and qp scalings cancel.
// ---------------------------------------------------------------------------

#define NN   50000
#define BB   4
#define TT   12
#define DDIM 3
#define EPSP 1e-4f
#define NRM  0.42044820762685725f   // 32^-0.25
#define NRM2 0.17677669529663687f   // 32^-0.5

#define DEV __device__ __forceinline__

DEV float bcast(float v, int lane) {
  return __int_as_float(__builtin_amdgcn_readlane(__float_as_int(v), lane));
}

template<int CTRL>
DEV float dpp_add(float x) {
  int p = __builtin_amdgcn_update_dpp(0, __float_as_int(x), CTRL, 0xF, 0xF, false);
  return x + __int_as_float(p);
}
template<int CTRL>
DEV float dpp_max(float x) {
  int p = __builtin_amdgcn_update_dpp(0, __float_as_int(x), CTRL, 0xF, 0xF, false);
  return fmaxf(x, __int_as_float(p));
}

// full-wave (64) sum: xor1, xor2 (quad_perm), xor7 (row_half_mirror),
// xor15 (row_mirror) -> each 16-row uniform; combine rows via readlane.
DEV float wave_sum(float x) {
  x = dpp_add<0xB1>(x);    // quad_perm [1,0,3,2]
  x = dpp_add<0x4E>(x);    // quad_perm [2,3,0,1]
  x = dpp_add<0x141>(x);   // row_half_mirror
  x = dpp_add<0x140>(x);   // row_mirror
  return (bcast(x, 0) + bcast(x, 16)) + (bcast(x, 32) + bcast(x, 48));
}
DEV float wave_max(float x) {
  x = dpp_max<0xB1>(x);
  x = dpp_max<0x4E>(x);
  x = dpp_max<0x141>(x);
  x = dpp_max<0x140>(x);
  return fmaxf(fmaxf(bcast(x, 0), bcast(x, 16)),
               fmaxf(bcast(x, 32), bcast(x, 48)));
}

// monotonic float<->uint encoding for atomicMax; memset(0) is a valid -inf.
DEV unsigned fenc(float f) {
  int i = __float_as_int(f);
  return (unsigned)(i ^ ((i >> 31) | 0x80000000));
}
DEV float fdec(unsigned u) {
  int i = (u & 0x80000000u) ? (int)(u ^ 0x80000000u) : ~(int)u;
  return __int_as_float(i);
}

// ---------------------------------------------------------------------------
// K0: per-node (batch-independent): nv1, nv2 -> qp[n][r], e_k[n][r],
//     E_ksum[r] (atomic), global max M of dd_k (atomicMax).
// ---------------------------------------------------------------------------
__global__ __launch_bounds__(256) void k_node(
    const float* __restrict__ node_emb,
    const float* __restrict__ w1, const float* __restrict__ b1,
    const float* __restrict__ w2, const float* __restrict__ b2,
    const float* __restrict__ rm1,
    float* __restrict__ qp_out, float* __restrict__ ek_out,
    float* __restrict__ eksum, unsigned* __restrict__ Mmax)
{
  const int lane = threadIdx.x & 63;
  const int j = lane & 31;
  const int gw = (blockIdx.x * 256 + threadIdx.x) >> 6;
  const int nw = (gridDim.x * 256) >> 6;

  float w1r[32], w2r[32], rmr[32];
  #pragma unroll
  for (int d = 0; d < 32; ++d) {
    w1r[d] = w1[j * 32 + d];
    w2r[d] = w2[j * 32 + d];
    rmr[d] = rm1[lane * 32 + d];   // rm1 row r=lane
  }
  const float b1v = b1[j], b2v = b2[j];

  float eks_acc = 0.f, mk_run = -1e30f;

  for (int n = gw; n < NN; n += nw) {
    float nd = node_emb[n * 32 + j];          // lanes duplicated per half
    float nv1 = b1v, nv2 = b2v;
    #pragma unroll
    for (int d = 0; d < 32; ++d) {
      float xv = bcast(nd, d);
      nv1 = fmaf(xv, w1r[d], nv1);
      nv2 = fmaf(xv, w2r[d], nv2);
    }
    // halves duplicated -> wave_sum = 2*sum; diag = 0.5*nrm2*sum
    float dq = wave_sum(nv1 * nv1) * (0.25f * NRM2);
    float dk = wave_sum(nv2 * nv2) * (0.25f * NRM2);
    float ddq = 0.f, ddk = 0.f;
    #pragma unroll
    for (int d = 0; d < 32; ++d) {
      ddq = fmaf(bcast(nv1, d), rmr[d], ddq);
      ddk = fmaf(bcast(nv2, d), rmr[d], ddk);
    }
    ddq *= NRM; ddk *= NRM;
    float mq = wave_max(ddq);                 // per-query max over r
    float qp = __expf(ddq - dq - mq) + EPSP;  // ratio dropped (cancels)
    float ek = __expf(ddk - dk);              // raw; exp(-M) applied later
    mk_run = fmaxf(mk_run, ddk);
    eks_acc += ek;
    qp_out[n * 64 + lane] = qp;
    ek_out[n * 64 + lane] = ek;
  }
  atomicAdd(&eksum[lane], eks_acc);
  float mw = wave_max(mk_run);
  if (lane == 0) atomicMax(Mmax, fenc(mw));
}

// ---------------------------------------------------------------------------
// K1: per-(b,n): xc -> v = relu(fc(xc)); accumulate E_kv[b][r][c] = sum e_k*v
//     and Vsum[b][c] = sum v. Register accumulator -> LDS block reduce ->
//     global atomics. Each block owns one batch (blockIdx&3).
// ---------------------------------------------------------------------------
__global__ __launch_bounds__(256) void k_kv(
    const float* __restrict__ x, const float* __restrict__ node_emb,
    const float* __restrict__ w_input, const float* __restrict__ b_input,
    const float* __restrict__ fc_w, const float* __restrict__ fc_b,
    const float* __restrict__ ek_in,
    float* __restrict__ E_kv, float* __restrict__ Vsum)
{
  const int lane = threadIdx.x & 63;
  const int wv = threadIdx.x >> 6;
  const int j = lane & 31;
  const int b = blockIdx.x & 3;
  const int wInB = (blockIdx.x >> 2) * 4 + wv;
  const int strideB = gridDim.x;              // == (gridDim/4)*4 waves/batch

  float wir[12];
  #pragma unroll
  for (int t = 0; t < 12; ++t) wir[t] = w_input[j * 12 + t];
  float fcr[64];
  #pragma unroll
  for (int c = 0; c < 64; ++c) fcr[c] = fc_w[lane * 64 + c];
  const float biv = b_input[j], fbv = fc_b[lane];

  float acc[64];
  #pragma unroll
  for (int r = 0; r < 64; ++r) acc[r] = 0.f;
  float vs_acc = 0.f;

  for (int n = wInB; n < NN; n += strideB) {
    const size_t xb = ((size_t)b * NN + n) * (TT * DDIM);
    float xt = (lane < 12) ? x[xb + lane * 3] : 0.f;   // x[b,n,t,0]
    float ie = biv;
    #pragma unroll
    for (int t = 0; t < 12; ++t) ie = fmaf(bcast(xt, t), wir[t], ie);
    float nd = node_emb[n * 32 + j];
    float xc = (lane < 32) ? ie : nd;
    float v = fbv;
    #pragma unroll
    for (int c = 0; c < 64; ++c) v = fmaf(bcast(xc, c), fcr[c], v);
    v = fmaxf(v, 0.f);
    float ek = ek_in[n * 64 + lane];
    #pragma unroll
    for (int r = 0; r < 64; ++r) acc[r] = fmaf(bcast(ek, r), v, acc[r]);
    vs_acc += v;
  }

  __shared__ float pkv[64][65];
  __shared__ float pvs[64];
  if (wv == 0) {
    #pragma unroll
    for (int r = 0; r < 64; ++r) pkv[r][lane] = acc[r];
    pvs[lane] = vs_acc;
  }
  __syncthreads();
  for (int w = 1; w < 4; ++w) {
    if (wv == w) {
      #pragma unroll
      for (int r = 0; r < 64; ++r) pkv[r][lane] += acc[r];
      pvs[lane] += vs_acc;
    }
    __syncthreads();
  }
  for (int i = threadIdx.x; i < 4096; i += 256)
    atomicAdd(&E_kv[b * 4096 + i], pkv[i >> 6][i & 63]);
  if (threadIdx.x < 64) atomicAdd(&Vsum[b * 64 + threadIdx.x], pvs[threadIdx.x]);
}

// ---------------------------------------------------------------------------
// K3: per-(b,n): num = qp @ kv, den = qp @ ksum, h = num/den + xc, LN,
//     out = relu([xc, h_ln]) @ w_reg^T + b_reg. kv finalized per wave:
//     kv = exp(-M)*E_kv + eps*Vsum; ksum = exp(-M)*E_ksum + eps*N.
//     Wave wv of each block handles batch wv; n strided by gridDim.
// ---------------------------------------------------------------------------
__global__ __launch_bounds__(256) void k_out(
    const float* __restrict__ x, const float* __restrict__ node_emb,
    const float* __restrict__ w_input, const float* __restrict__ b_input,
    const float* __restrict__ qp_in,
    const float* __restrict__ E_kv, const float* __restrict__ Vsum,
    const float* __restrict__ eksum, const unsigned* __restrict__ Mmax,
    const float* __restrict__ ln_g, const float* __restrict__ ln_b,
    const float* __restrict__ w_reg, const float* __restrict__ b_reg,
    float* __restrict__ out)
{
  const int lane = threadIdx.x & 63;
  const int b = threadIdx.x >> 6;             // wave index == batch
  const int j = lane & 31;
  const int w = blockIdx.x;
  const int stride = gridDim.x;

  const float s = __expf(-fdec(*Mmax));
  float wir[12];
  #pragma unroll
  for (int t = 0; t < 12; ++t) wir[t] = w_input[j * 12 + t];
  const float biv = b_input[j];
  float wA[12], wB[12];
  #pragma unroll
  for (int o = 0; o < 12; ++o) {
    wA[o] = w_reg[o * 128 + lane];
    wB[o] = w_reg[o * 128 + 64 + lane];
  }
  const float brv = (lane < 12) ? b_reg[lane] : 0.f;
  const float gv = ln_g[lane], bv = ln_b[lane];
  const float vs_e = EPSP * Vsum[b * 64 + lane];
  float kvr[64];
  #pragma unroll
  for (int r = 0; r < 64; ++r)
    kvr[r] = fmaf(s, E_kv[(b * 64 + r) * 64 + lane], vs_e);
  const float ks = fmaf(s, eksum[lane], EPSP * (float)NN);

  for (int n = w; n < NN; n += stride) {
    const size_t xb = ((size_t)b * NN + n) * (TT * DDIM);
    float xt = (lane < 12) ? x[xb + lane * 3] : 0.f;
    float ie = biv;
    #pragma unroll
    for (int t = 0; t < 12; ++t) ie = fmaf(bcast(xt, t), wir[t], ie);
    float nd = node_emb[n * 32 + j];
    float xc = (lane < 32) ? ie : nd;

    float qp = qp_in[n * 64 + lane];
    float num = 0.f;
    #pragma unroll
    for (int r = 0; r < 64; ++r) num = fmaf(bcast(qp, r), kvr[r], num);
    float den = wave_sum(qp * ks);
    float h = num / den + xc;

    float mean = wave_sum(h) * 0.015625f;
    float ctr = h - mean;
    float var = wave_sum(ctr * ctr) * 0.015625f;
    float hn = fmaf(ctr * rsqrtf(var + 1e-5f), gv, bv);

    float f1 = fmaxf(xc, 0.f), f2 = fmaxf(hn, 0.f);
    float vout = brv;
    #pragma unroll
    for (int o = 0; o < 12; ++o) {
      float so = wave_sum(fmaf(f1, wA[o], f2 * wB[o]));
      if (lane == o) vout += so;
    }
    if (lane < 12) out[((size_t)b * NN + n) * 12 + lane] = vout;
  }
}

// ---------------------------------------------------------------------------
extern "C" void kernel_launch(void* const* d_in, const int* in_sizes, int n_in,
                              void* d_out, int out_size, void* d_ws, size_t ws_size,
                              hipStream_t stream) {
  (void)in_sizes; (void)n_in; (void)out_size; (void)ws_size;
  const float* x       = (const float*)d_in[0];
  const float* node    = (const float*)d_in[1];
  const float* w_input = (const float*)d_in[4];
  const float* b_input = (const float*)d_in[5];
  const float* w1      = (const float*)d_in[6];
  const float* b1      = (const float*)d_in[7];
  const float* w2      = (const float*)d_in[8];
  const float* b2      = (const float*)d_in[9];
  const float* fc_w    = (const float*)d_in[14];
  const float* fc_b    = (const float*)d_in[15];
  const float* ln_g    = (const float*)d_in[18];
  const float* ln_b    = (const float*)d_in[19];
  const float* w_reg   = (const float*)d_in[22];
  const float* b_reg   = (const float*)d_in[23];
  const float* rm1     = (const float*)d_in[24];

  // workspace layout (floats):
  // [0,16384)      E_kv[4][64][64]
  // [16384,16640)  Vsum[4][64]
  // [16640,16704)  E_ksum[64]
  // [16704]        Mmax (uint, monotonic-encoded; 0 == -inf)
  // [16768, +3.2M) qp[N][64]
  // [.., +3.2M)    e_k[N][64]     -> total ~25.7 MB
  float* ws      = (float*)d_ws;
  float* E_kv    = ws;
  float* Vsum    = ws + 16384;
  float* E_ks    = ws + 16640;
  unsigned* Mmax = (unsigned*)(ws + 16704);
  float* qp      = ws + 16768;
  float* ek      = qp + (size_t)NN * 64;

  hipMemsetAsync(d_ws, 0, 16768 * sizeof(float), stream);
  k_node<<<512, 256, 0, stream>>>(node, w1, b1, w2, b2, rm1, qp, ek, E_ks, Mmax);
  k_kv<<<1024, 256, 0, stream>>>(x, node, w_input, b_input, fc_w, fc_b, ek, E_kv, Vsum);
  k_out<<<2048, 256, 0, stream>>>(x, node, w_input, b_input, qp, E_kv, Vsum, E_ks,
                                  Mmax, ln_g, ln_b, w_reg, b_reg, (float*)d_out);
}

// Round 3
// 349.422 us; speedup vs baseline: 1.3416x; 1.3416x over previous
//
#include <hip/hip_runtime.h>

// ---------------------------------------------------------------------------
// GSNet forward, live subgraph only (hk branch dead in reference).
// B=4, N=50000, T=12, HID=32, C=64, R=64.
// Round-3 redesign: eliminate cross-lane ops (readlane/DPP measured ~4.5cyc).
//  - per-node operands via uniform (readfirstlane) chunked loads -> SGPR/bcast
//  - W_eff = fc_A@W_in, g2[n] = fc_B@node + bias precomputed (batch-indep)
//  - k_out epilogue: LDS transpose, serial per-lane sums (no wave_sums)
// ---------------------------------------------------------------------------

#define NN   50000
#define EPSP 1e-4f
#define NRM  0.42044820762685725f   // 32^-0.25
#define HNRM2 0.08838834764831843f  // 0.5 * 32^-0.5

#define DEV __device__ __forceinline__

DEV float bcast(float v, int lane) {
  return __int_as_float(__builtin_amdgcn_readlane(__float_as_int(v), lane));
}
template<int CTRL>
DEV float dpp_add(float x) {
  int p = __builtin_amdgcn_update_dpp(0, __float_as_int(x), CTRL, 0xF, 0xF, false);
  return x + __int_as_float(p);
}
template<int CTRL>
DEV float dpp_max(float x) {
  int p = __builtin_amdgcn_update_dpp(0, __float_as_int(x), CTRL, 0xF, 0xF, false);
  return fmaxf(x, __int_as_float(p));
}
DEV float wave_sum(float x) {
  x = dpp_add<0xB1>(x); x = dpp_add<0x4E>(x);
  x = dpp_add<0x141>(x); x = dpp_add<0x140>(x);
  return (bcast(x, 0) + bcast(x, 16)) + (bcast(x, 32) + bcast(x, 48));
}
DEV float wave_max(float x) {
  x = dpp_max<0xB1>(x); x = dpp_max<0x4E>(x);
  x = dpp_max<0x141>(x); x = dpp_max<0x140>(x);
  return fmaxf(fmaxf(bcast(x, 0), bcast(x, 16)),
               fmaxf(bcast(x, 32), bcast(x, 48)));
}
DEV unsigned fenc(float f) {
  int i = __float_as_int(f);
  return (unsigned)(i ^ ((i >> 31) | 0x80000000));
}
DEV float fdec(unsigned u) {
  int i = (u & 0x80000000u) ? (int)(u ^ 0x80000000u) : ~(int)u;
  return __int_as_float(i);
}

// ---------------------------------------------------------------------------
// k_weff: W_eff[c][t] = sum_d fcA[c][d]*w_input[d][t];  beff[c] = fcA@b_in + fc_b
// ---------------------------------------------------------------------------
__global__ void k_weff(const float* __restrict__ fc_w,
                       const float* __restrict__ w_input,
                       const float* __restrict__ b_input,
                       const float* __restrict__ fc_b,
                       float* __restrict__ Weff, float* __restrict__ beff)
{
  const int c = threadIdx.x;  // 64 threads
  float fr[32];
  #pragma unroll
  for (int d = 0; d < 32; ++d) fr[d] = fc_w[c * 64 + d];
  #pragma unroll
  for (int t = 0; t < 12; ++t) {
    float s = 0.f;
    #pragma unroll
    for (int d = 0; d < 32; ++d) s = fmaf(fr[d], w_input[d * 12 + t], s);
    Weff[c * 12 + t] = s;
  }
  float s = fc_b[c];
  #pragma unroll
  for (int d = 0; d < 32; ++d) s = fmaf(fr[d], b_input[d], s);
  beff[c] = s;
}

// ---------------------------------------------------------------------------
// k_xpack: xp[b][n][t] = x[b][n][t][0]   (2,400,000 elems, grid exact)
// ---------------------------------------------------------------------------
__global__ __launch_bounds__(256) void k_xpack(const float* __restrict__ x,
                                               float* __restrict__ xp)
{
  const int i = blockIdx.x * 256 + threadIdx.x;
  xp[i] = x[(size_t)i * 3];
}

// ---------------------------------------------------------------------------
// k_node (batch-independent): nv1/nv2 (split halves), g2, qp, ek, eksum, Mmax
// ---------------------------------------------------------------------------
__global__ __launch_bounds__(256) void k_node(
    const float* __restrict__ node_emb,
    const float* __restrict__ w1, const float* __restrict__ b1,
    const float* __restrict__ w2, const float* __restrict__ b2,
    const float* __restrict__ rm1, const float* __restrict__ fc_w,
    const float* __restrict__ beff,
    float* __restrict__ qp_out, float* __restrict__ ek_out,
    float* __restrict__ g2_out,
    float* __restrict__ eksum, unsigned* __restrict__ Mmax)
{
  const int lane = threadIdx.x & 63;
  const int wv = threadIdx.x >> 6;
  const int j = lane & 31;
  const int gw = (blockIdx.x * 256 + threadIdx.x) >> 6;
  const int nw = (gridDim.x * 256) >> 6;

  __shared__ float nvs[4][68];

  float wrow[32], fbr[32], rmr[32];
  const float* wsel = (lane < 32) ? w1 : w2;
  #pragma unroll
  for (int d = 0; d < 32; ++d) {
    wrow[d] = wsel[j * 32 + d];
    fbr[d]  = fc_w[lane * 64 + 32 + d];
    rmr[d]  = rm1[lane * 32 + d];
  }
  const float bsel = (lane < 32) ? b1[j] : b2[j];
  const float be = beff[lane];

  float eks_acc = 0.f, mk_run = -3.0e38f;

  for (int n = gw; n < NN; n += nw) {
    const int nu = __builtin_amdgcn_readfirstlane(n);
    const float4* ne4 = (const float4*)(node_emb + (size_t)nu * 32);
    float nd0[32];
    #pragma unroll
    for (int k = 0; k < 8; ++k) {
      float4 c = ne4[k];
      nd0[4*k] = c.x; nd0[4*k+1] = c.y; nd0[4*k+2] = c.z; nd0[4*k+3] = c.w;
    }
    // nv (this lane's half), 4-way ILP
    float a0 = bsel, a1 = 0.f, a2 = 0.f, a3 = 0.f;
    #pragma unroll
    for (int d = 0; d < 32; d += 4) {
      a0 = fmaf(nd0[d],   wrow[d],   a0);
      a1 = fmaf(nd0[d+1], wrow[d+1], a1);
      a2 = fmaf(nd0[d+2], wrow[d+2], a2);
      a3 = fmaf(nd0[d+3], wrow[d+3], a3);
    }
    const float nv = (a0 + a1) + (a2 + a3);
    // g2 = fc_B @ node + beff
    float g0 = be, g1 = 0.f, g2a = 0.f, g3 = 0.f;
    #pragma unroll
    for (int d = 0; d < 32; d += 4) {
      g0 = fmaf(nd0[d],   fbr[d],   g0);
      g1 = fmaf(nd0[d+1], fbr[d+1], g1);
      g2a = fmaf(nd0[d+2], fbr[d+2], g2a);
      g3 = fmaf(nd0[d+3], fbr[d+3], g3);
    }
    g2_out[(size_t)nu * 64 + lane] = (g0 + g1) + (g2a + g3);
    // dq (lanes 0-31 hold nv1), dk (lanes 32-63 hold nv2)
    float t = nv * nv;
    t = dpp_add<0xB1>(t); t = dpp_add<0x4E>(t);
    t = dpp_add<0x141>(t); t = dpp_add<0x140>(t);
    const float dq = bcast(t, 0) + bcast(t, 16);
    const float dk = bcast(t, 32) + bcast(t, 48);
    // share nv across the wave via LDS (same-wave RAW, no barrier needed)
    nvs[wv][lane] = nv;
    float q0 = 0.f, q1 = 0.f, k0 = 0.f, k1 = 0.f;
    const float4* nv1p = (const float4*)&nvs[wv][0];
    const float4* nv2p = (const float4*)&nvs[wv][32];
    #pragma unroll
    for (int k = 0; k < 8; ++k) {
      float4 c = nv1p[k];
      q0 = fmaf(c.x, rmr[4*k],   q0); q1 = fmaf(c.y, rmr[4*k+1], q1);
      q0 = fmaf(c.z, rmr[4*k+2], q0); q1 = fmaf(c.w, rmr[4*k+3], q1);
    }
    #pragma unroll
    for (int k = 0; k < 8; ++k) {
      float4 c = nv2p[k];
      k0 = fmaf(c.x, rmr[4*k],   k0); k1 = fmaf(c.y, rmr[4*k+1], k1);
      k0 = fmaf(c.z, rmr[4*k+2], k0); k1 = fmaf(c.w, rmr[4*k+3], k1);
    }
    const float ddq = (q0 + q1) * NRM;
    const float ddk = (k0 + k1) * NRM;
    const float mq = wave_max(ddq);
    const float qpv = __expf(ddq - HNRM2 * dq - mq) + EPSP;
    const float ekv = __expf(ddk - HNRM2 * dk);
    mk_run = fmaxf(mk_run, ddk);
    eks_acc += ekv;
    qp_out[(size_t)nu * 64 + lane] = qpv;
    ek_out[(size_t)nu * 64 + lane] = ekv;
  }
  atomicAdd(&eksum[lane], eks_acc);
  const float mw = wave_max(mk_run);
  if (lane == 0) atomicMax(Mmax, fenc(mw));
}

// ---------------------------------------------------------------------------
// k_kv: v = relu(Weff@xt + g2[n]);  E_kv[b] += ek(n) (x) v;  Vsum[b] += v
// ---------------------------------------------------------------------------
__global__ __launch_bounds__(256) void k_kv(
    const float* __restrict__ xp, const float* __restrict__ Weff,
    const float* __restrict__ g2_in, const float* __restrict__ ek_in,
    float* __restrict__ E_kv, float* __restrict__ Vsum)
{
  const int lane = threadIdx.x & 63;
  const int wv = threadIdx.x >> 6;
  const int b = blockIdx.x & 3;
  const int wInB = (blockIdx.x >> 2) * 4 + wv;
  const int strideB = gridDim.x;   // (grid/4)*4 waves per batch

  float wrow[12];
  #pragma unroll
  for (int t = 0; t < 12; ++t) wrow[t] = Weff[lane * 12 + t];

  float acc[64];
  #pragma unroll
  for (int r = 0; r < 64; ++r) acc[r] = 0.f;
  float vs = 0.f;

  for (int n = wInB; n < NN; n += strideB) {
    const int nu = __builtin_amdgcn_readfirstlane(n);
    const float4* xp4 = (const float4*)(xp + ((size_t)b * NN + nu) * 12);
    float4 c0 = xp4[0], c1 = xp4[1], c2 = xp4[2];
    float v0 = fmaf(c0.x, wrow[0], g2_in[(size_t)nu * 64 + lane]);
    float v1 = c0.y * wrow[1], v2 = c0.z * wrow[2], v3 = c0.w * wrow[3];
    v0 = fmaf(c1.x, wrow[4], v0); v1 = fmaf(c1.y, wrow[5], v1);
    v2 = fmaf(c1.z, wrow[6], v2); v3 = fmaf(c1.w, wrow[7], v3);
    v0 = fmaf(c2.x, wrow[8], v0); v1 = fmaf(c2.y, wrow[9], v1);
    v2 = fmaf(c2.z, wrow[10], v2); v3 = fmaf(c2.w, wrow[11], v3);
    const float v = fmaxf((v0 + v1) + (v2 + v3), 0.f);
    const float4* ekp = (const float4*)(ek_in + (size_t)nu * 64);
    #pragma unroll
    for (int k = 0; k < 16; ++k) {
      float4 e = ekp[k];
      acc[4*k]   = fmaf(e.x, v, acc[4*k]);
      acc[4*k+1] = fmaf(e.y, v, acc[4*k+1]);
      acc[4*k+2] = fmaf(e.z, v, acc[4*k+2]);
      acc[4*k+3] = fmaf(e.w, v, acc[4*k+3]);
    }
    vs += v;
  }

  __shared__ float pkv[64][65];
  __shared__ float pvs[64];
  if (wv == 0) {
    #pragma unroll
    for (int r = 0; r < 64; ++r) pkv[r][lane] = acc[r];
    pvs[lane] = vs;
  }
  __syncthreads();
  for (int w = 1; w < 4; ++w) {
    if (wv == w) {
      #pragma unroll
      for (int r = 0; r < 64; ++r) pkv[r][lane] += acc[r];
      pvs[lane] += vs;
    }
    __syncthreads();
  }
  for (int i = threadIdx.x; i < 4096; i += 256)
    atomicAdd(&E_kv[b * 4096 + i], pkv[i >> 6][i & 63]);
  if (threadIdx.x < 64) atomicAdd(&Vsum[b * 64 + threadIdx.x], pvs[threadIdx.x]);
}

// ---------------------------------------------------------------------------
// k_out: per (b,n): num/den, +xc, LN, epilogue GEMV via LDS transpose.
// grid 3125 x 256: wave wid = blk*4+wv -> b = wid&3, chunk = wid>>2 (16 nodes)
// ---------------------------------------------------------------------------
__global__ __launch_bounds__(256) void k_out(
    const float* __restrict__ xp, const float* __restrict__ node_emb,
    const float* __restrict__ w_input, const float* __restrict__ b_input,
    const float* __restrict__ qp_in,
    const float* __restrict__ E_kv, const float* __restrict__ Vs,
    const float* __restrict__ eksum, const unsigned* __restrict__ Mmax,
    const float* __restrict__ ln_g, const float* __restrict__ ln_b,
    const float* __restrict__ w_reg, const float* __restrict__ b_reg,
    float* __restrict__ out)
{
  const int lane = threadIdx.x & 63;
  const int wv = threadIdx.x >> 6;
  const int j = lane & 31;
  const int wid = blockIdx.x * 4 + wv;   // < 12500
  const int b = wid & 3;
  const int n0 = (wid >> 2) * 16;

  __shared__ float pl[4][3280];          // [wave][slot*820 + o*68 + lane]
  float* plw = pl[wv];

  const float sc = __expf(-fdec(*Mmax));
  float wir[12];
  #pragma unroll
  for (int t = 0; t < 12; ++t) wir[t] = w_input[j * 12 + t];
  const float biv = b_input[j];
  float wA[12], wB[12];
  #pragma unroll
  for (int o = 0; o < 12; ++o) {
    wA[o] = w_reg[o * 128 + lane];
    wB[o] = w_reg[o * 128 + 64 + lane];
  }
  const float gv = ln_g[lane], bv = ln_b[lane];
  const float vse = EPSP * Vs[b * 64 + lane];
  float kvr[64];
  #pragma unroll
  for (int r = 0; r < 64; ++r)
    kvr[r] = fmaf(sc, E_kv[(b * 64 + r) * 64 + lane], vse);
  const float ks = fmaf(sc, eksum[lane], EPSP * (float)NN);
  const int slot = lane / 12;            // valid for lane<48
  const int oo = lane - slot * 12;
  const float brv = (lane < 48) ? b_reg[oo] : 0.f;

  for (int bt = 0; bt < 4; ++bt) {
    for (int s = 0; s < 4; ++s) {
      const int nu = __builtin_amdgcn_readfirstlane(n0 + bt * 4 + s);
      const float4* xp4 = (const float4*)(xp + ((size_t)b * NN + nu) * 12);
      float4 c0 = xp4[0], c1 = xp4[1], c2 = xp4[2];
      float e0 = fmaf(c0.x, wir[0], biv), e1 = c0.y * wir[1];
      float e2 = c0.z * wir[2], e3 = c0.w * wir[3];
      e0 = fmaf(c1.x, wir[4], e0); e1 = fmaf(c1.y, wir[5], e1);
      e2 = fmaf(c1.z, wir[6], e2); e3 = fmaf(c1.w, wir[7], e3);
      e0 = fmaf(c2.x, wir[8], e0); e1 = fmaf(c2.y, wir[9], e1);
      e2 = fmaf(c2.z, wir[10], e2); e3 = fmaf(c2.w, wir[11], e3);
      const float ie = (e0 + e1) + (e2 + e3);
      const float ndv = node_emb[(size_t)nu * 32 + j];
      const float xc = (lane < 32) ? ie : ndv;

      const float* qpp = qp_in + (size_t)nu * 64;
      const float4* qp4 = (const float4*)qpp;
      float m0 = 0.f, m1 = 0.f, m2 = 0.f, m3 = 0.f;
      #pragma unroll
      for (int k = 0; k < 16; ++k) {
        float4 q = qp4[k];
        m0 = fmaf(q.x, kvr[4*k],   m0);
        m1 = fmaf(q.y, kvr[4*k+1], m1);
        m2 = fmaf(q.z, kvr[4*k+2], m2);
        m3 = fmaf(q.w, kvr[4*k+3], m3);
      }
      const float num = (m0 + m1) + (m2 + m3);
      const float qv = qpp[lane];
      const float den = wave_sum(qv * ks);
      const float h = num / den + xc;

      const float mean = wave_sum(h) * 0.015625f;
      const float ctr = h - mean;
      const float var = wave_sum(ctr * ctr) * 0.015625f;
      const float hn = fmaf(ctr * rsqrtf(var + 1e-5f), gv, bv);
      const float f1 = fmaxf(xc, 0.f), f2 = fmaxf(hn, 0.f);

      float* pls = plw + s * 820 + lane;
      #pragma unroll
      for (int o = 0; o < 12; ++o)
        pls[o * 68] = fmaf(f1, wA[o], f2 * wB[o]);
    }
    if (lane < 48) {
      const float4* pr = (const float4*)(plw + slot * 820 + oo * 68);
      float s0 = 0.f, s1 = 0.f, s2 = 0.f, s3 = 0.f;
      #pragma unroll
      for (int k = 0; k < 16; ++k) {
        float4 c = pr[k];
        s0 += c.x; s1 += c.y; s2 += c.z; s3 += c.w;
      }
      const float r = (s0 + s1) + (s2 + s3) + brv;
      const int n = n0 + bt * 4 + slot;
      out[((size_t)b * NN + n) * 12 + oo] = r;
    }
  }
}

// ---------------------------------------------------------------------------
extern "C" void kernel_launch(void* const* d_in, const int* in_sizes, int n_in,
                              void* d_out, int out_size, void* d_ws, size_t ws_size,
                              hipStream_t stream) {
  (void)in_sizes; (void)n_in; (void)out_size; (void)ws_size;
  const float* x       = (const float*)d_in[0];
  const float* node    = (const float*)d_in[1];
  const float* w_input = (const float*)d_in[4];
  const float* b_input = (const float*)d_in[5];
  const float* w1      = (const float*)d_in[6];
  const float* b1      = (const float*)d_in[7];
  const float* w2      = (const float*)d_in[8];
  const float* b2      = (const float*)d_in[9];
  const float* fc_w    = (const float*)d_in[14];
  const float* fc_b    = (const float*)d_in[15];
  const float* ln_g    = (const float*)d_in[18];
  const float* ln_b    = (const float*)d_in[19];
  const float* w_reg   = (const float*)d_in[22];
  const float* b_reg   = (const float*)d_in[23];
  const float* rm1     = (const float*)d_in[24];

  // workspace (floats): E_kv[4][64][64] | Vsum[4][64] | eksum[64] | Mmax |
  //   Weff[64][12] | beff[64] | qp[N][64] | ek[N][64] | g2[N][64] | xp[4][N][12]
  float* ws      = (float*)d_ws;
  float* E_kv    = ws;
  float* Vsum    = ws + 16384;
  float* eksum   = ws + 16640;
  unsigned* Mmax = (unsigned*)(ws + 16704);
  float* Weff    = ws + 16768;
  float* beff    = ws + 17536;
  float* qp      = ws + 17600;
  float* ek      = ws + 3217600;
  float* g2      = ws + 6417600;
  float* xp      = ws + 9617600;   // end 12,017,600 floats = 48.1 MB

  hipMemsetAsync(d_ws, 0, 16768 * sizeof(float), stream);
  k_weff<<<1, 64, 0, stream>>>(fc_w, w_input, b_input, fc_b, Weff, beff);
  k_xpack<<<9375, 256, 0, stream>>>(x, xp);
  k_node<<<512, 256, 0, stream>>>(node, w1, b1, w2, b2, rm1, fc_w, beff,
                                  qp, ek, g2, eksum, Mmax);
  k_kv<<<1024, 256, 0, stream>>>(xp, Weff, g2, ek, E_kv, Vsum);
  k_out<<<3125, 256, 0, stream>>>(xp, node, w_input, b_input, qp, E_kv, Vsum,
                                  eksum, Mmax, ln_g, ln_b, w_reg, b_reg,
                                  (float*)d_out);
}